// Round 8
// baseline (490.988 us; speedup 1.0000x reference)
//
#include <hip/hip_runtime.h>
#include <hip/hip_fp16.h>
#include <cstdint>
#include <cstddef>

#define B_  32
#define N_  512
#define T_  24
#define F_  64
#define FA_ 74
#define NC  1536   // T_*F_ columns per node-row

typedef __attribute__((ext_vector_type(8))) _Float16 half8;
typedef __attribute__((ext_vector_type(8))) unsigned short ushort8;
typedef __attribute__((ext_vector_type(4))) float floatx4;
typedef __attribute__((ext_vector_type(2))) float floatx2;

// ws float layout:
//  [0,74)               rsW (rowsum of W)
//  [128,704)            W2 (symmetric, row-major 24x24)
//  [1536,132608)        adjH f16[512*512]  = 0.125*sig(alpha_i)*adj[i][k]
//  [132608,12715520)    xT  f16[b][c][k]   (32*1536*512 f16 = 12582912 floats, ~48 MB)
//  [12715520,13108736)  S   fp32[b][t][k]  (rowsum over f of x)  1.5 MB
#define WS_ADJ 1536
#define WS_XT  132608
#define WS_S   12715520   // = WS_XT + 32*1536*512/2 floats  (round-7 bug: was 6424064, inside xT!)

#define AS1(p) ((const __attribute__((address_space(1))) void*)(p))
#define AS3(p) ((__attribute__((address_space(3))) void*)(p))

union h2u { _Float16 h; unsigned short u; };

// One dispatch, 3 block types:
//  [0,6144)    x[b][k][c] fp32 -> xT[b][c][k] f16 (64x64 tiles) + S rowsums
//  [6144,6400) adj fp32 -> f16 scaled by 0.125*sigmoid(alpha_i)
//  [6400]      rsW + W2 param precompute
__global__ __launch_bounds__(256) void prep_kernel(
    const float* __restrict__ x, const float* __restrict__ adj,
    const float* __restrict__ alpha, const float* __restrict__ w,
    const float* __restrict__ d, const float* __restrict__ w2,
    const float* __restrict__ d2, float* __restrict__ ws) {
  __shared__ float tile[64 * 65];
  __shared__ float cs[FA_];
  int bid = blockIdx.x;
  int tid = threadIdx.x;
  if (bid < 6144) {
    _Float16* xT = (_Float16*)(ws + WS_XT);
    float* Sp = ws + WS_S;
    int ct = bid % 24;            // this c-tile is exactly t = ct
    int kt = (bid / 24) % 8;
    int b = bid / 192;
    int c0 = ct * 64;
    int k0 = kt * 64;
#pragma unroll
    for (int it = 0; it < 4; ++it) {
      int g = it * 256 + tid;
      int k = g >> 4, c4 = g & 15;
      float4 v = *(const float4*)&x[((size_t)(b * N_ + k0 + k)) * NC + c0 + c4 * 4];
      tile[k * 65 + c4 * 4 + 0] = v.x;
      tile[k * 65 + c4 * 4 + 1] = v.y;
      tile[k * 65 + c4 * 4 + 2] = v.z;
      tile[k * 65 + c4 * 4 + 3] = v.w;
    }
    __syncthreads();
    {
      // S[b][ct][k0+k] = sum_f tile[k][f] ; thread-quad (k, q) sums 16 each
      int k = tid >> 2, q = tid & 3;
      float s = 0.f;
#pragma unroll
      for (int j = 0; j < 16; ++j) s += tile[k * 65 + q * 16 + j];
      s += __shfl_xor(s, 1, 64);
      s += __shfl_xor(s, 2, 64);
      if (q == 0) Sp[((size_t)b * T_ + ct) * N_ + k0 + k] = s;
    }
#pragma unroll
    for (int it = 0; it < 4; ++it) {
      int hh = it * 256 + tid;
      int c = hh >> 4, k4 = hh & 15;
      ushort4 u4; h2u cv;
      cv.h = (_Float16)tile[(k4 * 4 + 0) * 65 + c]; u4.x = cv.u;
      cv.h = (_Float16)tile[(k4 * 4 + 1) * 65 + c]; u4.y = cv.u;
      cv.h = (_Float16)tile[(k4 * 4 + 2) * 65 + c]; u4.z = cv.u;
      cv.h = (_Float16)tile[(k4 * 4 + 3) * 65 + c]; u4.w = cv.u;
      *(ushort4*)&xT[((size_t)b * NC + c0 + c) * 512 + k0 + k4 * 4] = u4;
    }
  } else if (bid < 6400) {
    _Float16* adjH = (_Float16*)(ws + WS_ADJ);
    int g = ((bid - 6144) * 256 + tid) * 4;
    int row = g >> 9;
    float sc = 0.125f / (1.f + __expf(-alpha[row]));
    float4 v = *(const float4*)&adj[g];
    ushort4 u4; h2u cv;
    cv.h = (_Float16)(sc * v.x); u4.x = cv.u;
    cv.h = (_Float16)(sc * v.y); u4.y = cv.u;
    cv.h = (_Float16)(sc * v.z); u4.z = cv.u;
    cv.h = (_Float16)(sc * v.w); u4.w = cv.u;
    *(ushort4*)&adjH[g] = u4;
  } else {
    if (tid < FA_) {
      float s = 0.f;
      for (int n = 0; n < FA_; ++n) s += w[n * FA_ + tid];
      cs[tid] = s;
    }
    __syncthreads();
    if (tid < FA_) {
      float s = 0.f;
      for (int p = 0; p < FA_; ++p) {
        float dc = fminf(fmaxf(d[p], 0.f), 1.f);
        s += w[tid * FA_ + p] * dc * cs[p];
      }
      ws[tid] = s;
    }
    for (int e = tid; e < T_ * T_; e += 256) {
      int a = e / T_, b = e % T_;
      float s = 0.f;
      for (int p = 0; p < T_; ++p) {
        float dc = fminf(fmaxf(d2[p], 0.f), 1.f);
        s += w2[a * T_ + p] * dc * w2[b * T_ + p];
      }
      ws[128 + e] = s;
    }
  }
}

// MFMA GEMM + fused epilogue:
//   acc = (0.125*sig(a)*adj) @ x  (f16 MFMA, 128x128 tile, K=512, BK=64)
//   out = relu(acc + 0.25*tmix'(x) + 0.25*S*rsW[f])  (tmix' folds the 0.5*x)
//   from natural-layout fp32 x (float4 f-quad loads, L2-served) + precomputed S.
//   Aug channels f>=64 fused. Write-once. grid 1536 (XCD-chunked), 256 thr.
__global__ __launch_bounds__(256) void gemm_kernel(
    const float* __restrict__ ws, const float* __restrict__ x,
    float* __restrict__ out) {
  const _Float16* adjH = (const _Float16*)(ws + WS_ADJ);
  const _Float16* xT   = (const _Float16*)(ws + WS_XT);
  const float* Sp      = ws + WS_S;

  // smem: main loop As[0,16384) Bs[16384,32768); epilogue accS fp32 128x132
  __shared__ __align__(16) char smem[67584];
  _Float16* As = (_Float16*)smem;
  _Float16* Bs = (_Float16*)(smem + 16384);
  float* accS = (float*)smem;
  __shared__ float coefs[48];

  // XCD-chunked decode: xcd = raw&7 owns 192 consecutive logical blocks;
  // logical order: i fastest (4), then c (12), then b (4 per XCD).
  int raw = blockIdx.x;
  int nid = (raw & 7) * 192 + (raw >> 3);
  int iq = nid & 3;
  int rest = nid >> 2;
  int cb = rest % 12;
  int b = rest / 12;
  int i0 = iq * 128;
  int c0 = cb * 128;
  int t0 = cb * 2;

  int tid = threadIdx.x;
  int wave = tid >> 6, lane = tid & 63;
  int mw = (wave & 1) * 64, nw = (wave >> 1) * 64;
  int l15 = lane & 15, l4 = lane >> 4;

  // tmix coefficients: 0.25*W2[t0+tl][tp] + 0.5 at tp==t (folds 0.5*x term)
  if (tid < 48) {
    int tl = tid / 24, tp = tid - (tid / 24) * 24;
    float cf = 0.25f * ws[128 + (t0 + tl) * 24 + tp];
    if (tp == t0 + tl) cf += 0.5f;
    coefs[tid] = cf;
  }

  floatx4 acc[4][4];
#pragma unroll
  for (int mt = 0; mt < 4; ++mt)
#pragma unroll
    for (int nt = 0; nt < 4; ++nt) acc[mt][nt] = (floatx4){0.f, 0.f, 0.f, 0.f};

  const size_t bC = (size_t)b * NC;
  for (int k0 = 0; k0 < 512; k0 += 64) {
#pragma unroll
    for (int rep = 0; rep < 4; ++rep) {
      int chunk = rep * 256 + tid;       // 1024 chunks of 16B per matrix
      int r = chunk >> 3;                // row 0..127
      int s = chunk & 7;                 // 16B slot in row
      int ss = (s ^ (r & 7)) * 8;        // swizzled source k-offset (f16 units)
      __builtin_amdgcn_global_load_lds(AS1(adjH + (size_t)(i0 + r) * 512 + k0 + ss),
                                       AS3(&As[chunk * 8]), 16, 0, 0);
      __builtin_amdgcn_global_load_lds(AS1(xT + (bC + c0 + r) * 512 + k0 + ss),
                                       AS3(&Bs[chunk * 8]), 16, 0, 0);
    }
    __syncthreads();
#pragma unroll
    for (int ks = 0; ks < 2; ++ks) {
      half8 af[4], bfv[4];
#pragma unroll
      for (int mt = 0; mt < 4; ++mt) {
        int row = mw + mt * 16 + l15;
        int slot = (ks * 4 + l4) ^ (row & 7);
        af[mt] = *(const half8*)&As[row * 64 + slot * 8];
      }
#pragma unroll
      for (int nt = 0; nt < 4; ++nt) {
        int row = nw + nt * 16 + l15;
        int slot = (ks * 4 + l4) ^ (row & 7);
        bfv[nt] = *(const half8*)&Bs[row * 64 + slot * 8];
      }
#pragma unroll
      for (int mt = 0; mt < 4; ++mt)
#pragma unroll
        for (int nt = 0; nt < 4; ++nt)
          acc[mt][nt] = __builtin_amdgcn_mfma_f32_16x16x32_f16(af[mt], bfv[nt], acc[mt][nt], 0, 0, 0);
    }
    __syncthreads();
  }

  // Spill ALL acc -> accS[128][132] (acc regs die here, freeing VGPR)
#pragma unroll
  for (int mt = 0; mt < 4; ++mt)
#pragma unroll
    for (int nt = 0; nt < 4; ++nt)
#pragma unroll
      for (int r = 0; r < 4; ++r)
        accS[(mw + mt * 16 + l4 * 4 + r) * 132 + nw + nt * 16 + l15] = acc[mt][nt][r];
  __syncthreads();

  // Epilogue: thread = (rslot, f-quad). 8 iters x 16 rows cover 128 rows.
  const size_t bN = (size_t)b * N_;
  int fq = tid & 15;          // f = fq*4
  int rslot = tid >> 4;       // 0..15
  floatx4 rsW4 = *(const floatx4*)&ws[fq * 4];
  float rsWa = (fq < 10) ? ws[64 + fq] : 0.f;
  const float* SpT = Sp + ((size_t)b * T_ + t0) * N_;

#pragma unroll 2
  for (int ii = 0; ii < 8; ++ii) {
    int row = ii * 16 + rslot;
    int grow = i0 + row;
    const float* xr = x + (bN + grow) * NC + fq * 4;
    floatx4 xv[24];
#pragma unroll
    for (int tp = 0; tp < 24; ++tp) xv[tp] = *(const floatx4*)&xr[tp * 64];
    float s0 = SpT[grow];
    float s1 = SpT[N_ + grow];
    floatx4 tm0 = (floatx4){0.f, 0.f, 0.f, 0.f};
    floatx4 tm1 = (floatx4){0.f, 0.f, 0.f, 0.f};
#pragma unroll
    for (int tp = 0; tp < 24; ++tp) {
      tm0 += coefs[tp] * xv[tp];
      tm1 += coefs[24 + tp] * xv[tp];
    }
    floatx4 a0 = *(const floatx4*)&accS[row * 132 + fq * 4];
    floatx4 a1 = *(const floatx4*)&accS[row * 132 + 64 + fq * 4];
    floatx4 v0 = a0 + tm0 + (0.25f * s0) * rsW4;
    floatx4 v1 = a1 + tm1 + (0.25f * s1) * rsW4;
#pragma unroll
    for (int j = 0; j < 4; ++j) {
      v0[j] = fmaxf(v0[j], 0.f);
      v1[j] = fmaxf(v1[j], 0.f);
    }
    size_t ob = ((bN + grow) * T_ + t0) * FA_;
    *(floatx4*)&out[ob + fq * 4] = v0;
    // t0+1 row is 296B offset -> only 8B aligned: two float2 stores
    *(floatx2*)&out[ob + FA_ + fq * 4]     = (floatx2){v1[0], v1[1]};
    *(floatx2*)&out[ob + FA_ + fq * 4 + 2] = (floatx2){v1[2], v1[3]};
    if (fq < 10) {   // aug channel m == fq
      out[ob + 64 + fq]       = fmaxf(0.25f * s0 * rsWa, 0.f);
      out[ob + FA_ + 64 + fq] = fmaxf(0.25f * s1 * rsWa, 0.f);
    }
  }
}

extern "C" void kernel_launch(void* const* d_in, const int* in_sizes, int n_in,
                              void* d_out, int out_size, void* d_ws, size_t ws_size,
                              hipStream_t stream) {
  const float* x     = (const float*)d_in[0];
  const float* adj   = (const float*)d_in[1];
  const float* alpha = (const float*)d_in[2];
  const float* w     = (const float*)d_in[3];
  const float* d     = (const float*)d_in[4];
  const float* w2    = (const float*)d_in[5];
  const float* d2    = (const float*)d_in[6];
  float* out = (float*)d_out;
  float* ws  = (float*)d_ws;

  hipLaunchKernelGGL(prep_kernel, dim3(6401), dim3(256), 0, stream,
                     x, adj, alpha, w, d, w2, d2, ws);
  hipLaunchKernelGGL(gemm_kernel, dim3(1536), dim3(256), 0, stream, ws, x, out);
}

// Round 9
// 325.192 us; speedup vs baseline: 1.5098x; 1.5098x over previous
//
#include <hip/hip_runtime.h>
#include <hip/hip_fp16.h>
#include <cstdint>
#include <cstddef>

#define B_  32
#define N_  512
#define T_  24
#define F_  64
#define FA_ 74
#define NC  1536   // T_*F_ columns per node-row

typedef __attribute__((ext_vector_type(8))) _Float16 half8;
typedef __attribute__((ext_vector_type(8))) unsigned short ushort8;
typedef __attribute__((ext_vector_type(4))) float floatx4;

// ws float layout:
//  [0,74)               rsW (rowsum of W)
//  [128,704)            W2 (symmetric, row-major 24x24)
//  [1536,132608)        adjH f16[512*512]  = 0.125*sig(alpha_i)*adj[i][k]
//  [132608,12715520)    xT  f16[b][c][k]   (32*1536*512 f16 = 12582912 floats, ~48 MB)
//  [12715520,13108736)  S   fp32[b][t][k]  (rowsum over f of x)  1.5 MB
#define WS_ADJ 1536
#define WS_XT  132608
#define WS_S   12715520

#define AS1(p) ((const __attribute__((address_space(1))) void*)(p))
#define AS3(p) ((__attribute__((address_space(3))) void*)(p))

union h2u { _Float16 h; unsigned short u; };

// One dispatch, 3 block types:
//  [0,6144)    x[b][k][c] fp32 -> xT[b][c][k] f16 (64x64 tiles) + S rowsums
//  [6144,6400) adj fp32 -> f16 scaled by 0.125*sigmoid(alpha_i)
//  [6400]      rsW + W2 param precompute
__global__ __launch_bounds__(256) void prep_kernel(
    const float* __restrict__ x, const float* __restrict__ adj,
    const float* __restrict__ alpha, const float* __restrict__ w,
    const float* __restrict__ d, const float* __restrict__ w2,
    const float* __restrict__ d2, float* __restrict__ ws) {
  __shared__ float tile[64 * 65];
  __shared__ float cs[FA_];
  int bid = blockIdx.x;
  int tid = threadIdx.x;
  if (bid < 6144) {
    _Float16* xT = (_Float16*)(ws + WS_XT);
    float* Sp = ws + WS_S;
    int ct = bid % 24;            // this c-tile is exactly t = ct
    int kt = (bid / 24) % 8;
    int b = bid / 192;
    int c0 = ct * 64;
    int k0 = kt * 64;
#pragma unroll
    for (int it = 0; it < 4; ++it) {
      int g = it * 256 + tid;
      int k = g >> 4, c4 = g & 15;
      float4 v = *(const float4*)&x[((size_t)(b * N_ + k0 + k)) * NC + c0 + c4 * 4];
      tile[k * 65 + c4 * 4 + 0] = v.x;
      tile[k * 65 + c4 * 4 + 1] = v.y;
      tile[k * 65 + c4 * 4 + 2] = v.z;
      tile[k * 65 + c4 * 4 + 3] = v.w;
    }
    __syncthreads();
    {
      // S[b][ct][k0+k] = sum_f tile[k][f] ; thread-quad (k, q) sums 16 each
      int k = tid >> 2, q = tid & 3;
      float s = 0.f;
#pragma unroll
      for (int j = 0; j < 16; ++j) s += tile[k * 65 + q * 16 + j];
      s += __shfl_xor(s, 1, 64);
      s += __shfl_xor(s, 2, 64);
      if (q == 0) Sp[((size_t)b * T_ + ct) * N_ + k0 + k] = s;
    }
#pragma unroll
    for (int it = 0; it < 4; ++it) {
      int hh = it * 256 + tid;
      int c = hh >> 4, k4 = hh & 15;
      ushort4 u4; h2u cv;
      cv.h = (_Float16)tile[(k4 * 4 + 0) * 65 + c]; u4.x = cv.u;
      cv.h = (_Float16)tile[(k4 * 4 + 1) * 65 + c]; u4.y = cv.u;
      cv.h = (_Float16)tile[(k4 * 4 + 2) * 65 + c]; u4.z = cv.u;
      cv.h = (_Float16)tile[(k4 * 4 + 3) * 65 + c]; u4.w = cv.u;
      *(ushort4*)&xT[((size_t)b * NC + c0 + c) * 512 + k0 + k4 * 4] = u4;
    }
  } else if (bid < 6400) {
    _Float16* adjH = (_Float16*)(ws + WS_ADJ);
    int g = ((bid - 6144) * 256 + tid) * 4;
    int row = g >> 9;
    float sc = 0.125f / (1.f + __expf(-alpha[row]));
    float4 v = *(const float4*)&adj[g];
    ushort4 u4; h2u cv;
    cv.h = (_Float16)(sc * v.x); u4.x = cv.u;
    cv.h = (_Float16)(sc * v.y); u4.y = cv.u;
    cv.h = (_Float16)(sc * v.z); u4.z = cv.u;
    cv.h = (_Float16)(sc * v.w); u4.w = cv.u;
    *(ushort4*)&adjH[g] = u4;
  } else {
    if (tid < FA_) {
      float s = 0.f;
      for (int n = 0; n < FA_; ++n) s += w[n * FA_ + tid];
      cs[tid] = s;
    }
    __syncthreads();
    if (tid < FA_) {
      float s = 0.f;
      for (int p = 0; p < FA_; ++p) {
        float dc = fminf(fmaxf(d[p], 0.f), 1.f);
        s += w[tid * FA_ + p] * dc * cs[p];
      }
      ws[tid] = s;
    }
    for (int e = tid; e < T_ * T_; e += 256) {
      int a = e / T_, b = e % T_;
      float s = 0.f;
      for (int p = 0; p < T_; ++p) {
        float dc = fminf(fmaxf(d2[p], 0.f), 1.f);
        s += w2[a * T_ + p] * dc * w2[b * T_ + p];
      }
      ws[128 + e] = s;
    }
  }
}

// MFMA GEMM + fused epilogue (round-6 verified structure + precomputed-S loads):
//   acc = (0.125*sig(a)*adj) @ x  (f16 MFMA, 128x128 tile, K=512, BK=64)
//   out = relu(acc + 0.25*tmix'(x) + 0.25*S*rsW[f]); aug f>=64 fused; write-once.
//   grid 1536 (XCD-chunked), 256 thr.
__global__ __launch_bounds__(256) void gemm_kernel(
    const float* __restrict__ ws, const float* __restrict__ x,
    float* __restrict__ out) {
  const _Float16* adjH = (const _Float16*)(ws + WS_ADJ);
  const _Float16* xT   = (const _Float16*)(ws + WS_XT);
  const float* Sp      = ws + WS_S;

  // smem: main loop As[0,16384) Bs[16384,32768); epilogue accS fp32 64x132
  __shared__ __align__(16) char smem[33792];
  _Float16* As = (_Float16*)smem;
  _Float16* Bs = (_Float16*)(smem + 16384);
  float* accS = (float*)smem;
  __shared__ float coefs[48];

  // XCD-chunked decode: xcd = raw&7 owns 192 consecutive logical blocks;
  // logical order: i fastest (4), then c (12), then b (4 per XCD).
  int raw = blockIdx.x;
  int nid = (raw & 7) * 192 + (raw >> 3);
  int iq = nid & 3;
  int rest = nid >> 2;
  int cb = rest % 12;
  int b = rest / 12;
  int i0 = iq * 128;
  int c0 = cb * 128;
  int t0 = cb * 2;

  int tid = threadIdx.x;
  int wave = tid >> 6, lane = tid & 63;
  int mw = (wave & 1) * 64, nw = (wave >> 1) * 64;
  int l15 = lane & 15, l4 = lane >> 4;

  // tmix coefficients: 0.25*W2[t0+tl][tp] + 0.5 at tp==t (folds 0.5*x term)
  if (tid < 48) {
    int tl = tid / 24, tp = tid - (tid / 24) * 24;
    float cf = 0.25f * ws[128 + (t0 + tl) * 24 + tp];
    if (tp == t0 + tl) cf += 0.5f;
    coefs[tid] = cf;
  }

  floatx4 acc[4][4];
#pragma unroll
  for (int mt = 0; mt < 4; ++mt)
#pragma unroll
    for (int nt = 0; nt < 4; ++nt) acc[mt][nt] = (floatx4){0.f, 0.f, 0.f, 0.f};

  const size_t bC = (size_t)b * NC;
  for (int k0 = 0; k0 < 512; k0 += 64) {
#pragma unroll
    for (int rep = 0; rep < 4; ++rep) {
      int chunk = rep * 256 + tid;       // 1024 chunks of 16B per matrix
      int r = chunk >> 3;                // row 0..127
      int s = chunk & 7;                 // 16B slot in row
      int ss = (s ^ (r & 7)) * 8;        // swizzled source k-offset (f16 units)
      __builtin_amdgcn_global_load_lds(AS1(adjH + (size_t)(i0 + r) * 512 + k0 + ss),
                                       AS3(&As[chunk * 8]), 16, 0, 0);
      __builtin_amdgcn_global_load_lds(AS1(xT + (bC + c0 + r) * 512 + k0 + ss),
                                       AS3(&Bs[chunk * 8]), 16, 0, 0);
    }
    __syncthreads();
#pragma unroll
    for (int ks = 0; ks < 2; ++ks) {
      half8 af[4], bfv[4];
#pragma unroll
      for (int mt = 0; mt < 4; ++mt) {
        int row = mw + mt * 16 + l15;
        int slot = (ks * 4 + l4) ^ (row & 7);
        af[mt] = *(const half8*)&As[row * 64 + slot * 8];
      }
#pragma unroll
      for (int nt = 0; nt < 4; ++nt) {
        int row = nw + nt * 16 + l15;
        int slot = (ks * 4 + l4) ^ (row & 7);
        bfv[nt] = *(const half8*)&Bs[row * 64 + slot * 8];
      }
#pragma unroll
      for (int mt = 0; mt < 4; ++mt)
#pragma unroll
        for (int nt = 0; nt < 4; ++nt)
          acc[mt][nt] = __builtin_amdgcn_mfma_f32_16x16x32_f16(af[mt], bfv[nt], acc[mt][nt], 0, 0, 0);
    }
    __syncthreads();
  }

  // Epilogue: two 64-row halves. h=0 -> waves 0,2 (mw=0); h=1 -> waves 1,3.
  const size_t bN = (size_t)b * N_;
  int f = tid & 63;
  int rj = tid >> 6;
  float rsWf = ws[f];
  float rsWa = (f < 10) ? ws[64 + f] : 0.f;
  const float* SpT = Sp + ((size_t)b * T_ + t0) * N_;
  for (int h = 0; h < 2; ++h) {
    if ((wave & 1) == h) {
#pragma unroll
      for (int mt = 0; mt < 4; ++mt)
#pragma unroll
        for (int nt = 0; nt < 4; ++nt)
#pragma unroll
          for (int r = 0; r < 4; ++r)
            accS[(mt * 16 + l4 * 4 + r) * 132 + nw + nt * 16 + l15] = acc[mt][nt][r];
    }
    __syncthreads();

#pragma unroll 2
    for (int jj = 0; jj < 16; ++jj) {
      int row = rj + 4 * jj;
      int grow = i0 + h * 64 + row;
      const float* xr = x + (bN + grow) * NC;
      float xv[24];
#pragma unroll
      for (int tp = 0; tp < 24; ++tp) xv[tp] = xr[tp * 64 + f];  // 256B/wave
      float s0 = SpT[grow];          // wave-uniform broadcast loads
      float s1 = SpT[N_ + grow];
      float tm0 = 0.f, tm1 = 0.f;
#pragma unroll
      for (int tp = 0; tp < 24; ++tp) {
        tm0 += coefs[tp] * xv[tp];
        tm1 += coefs[24 + tp] * xv[tp];
      }
      float v0 = accS[row * 132 + f]      + tm0 + 0.25f * s0 * rsWf;
      float v1 = accS[row * 132 + 64 + f] + tm1 + 0.25f * s1 * rsWf;
      size_t o = ((bN + grow) * T_ + t0) * FA_ + f;
      out[o] = fmaxf(v0, 0.f);
      out[o + FA_] = fmaxf(v1, 0.f);
      if (f < 10) {   // aug channel m == f: addr is o + 64 (since o ends in +f)
        out[o + 64] = fmaxf(0.25f * s0 * rsWa, 0.f);
        out[o + FA_ + 64] = fmaxf(0.25f * s1 * rsWa, 0.f);
      }
    }
    __syncthreads();   // before next h overwrites accS
  }
}

extern "C" void kernel_launch(void* const* d_in, const int* in_sizes, int n_in,
                              void* d_out, int out_size, void* d_ws, size_t ws_size,
                              hipStream_t stream) {
  const float* x     = (const float*)d_in[0];
  const float* adj   = (const float*)d_in[1];
  const float* alpha = (const float*)d_in[2];
  const float* w     = (const float*)d_in[3];
  const float* d     = (const float*)d_in[4];
  const float* w2    = (const float*)d_in[5];
  const float* d2    = (const float*)d_in[6];
  float* out = (float*)d_out;
  float* ws  = (float*)d_ws;

  hipLaunchKernelGGL(prep_kernel, dim3(6401), dim3(256), 0, stream,
                     x, adj, alpha, w, d, w2, d2, ws);
  hipLaunchKernelGGL(gemm_kernel, dim3(1536), dim3(256), 0, stream, ws, x, out);
}